// Round 6
// baseline (189.601 us; speedup 1.0000x reference)
//
#include <hip/hip_runtime.h>

#define NBINS 15
#define NTHREADS 256
#define NWAVES 4
#define NBLOCKS 2048
#define TT (NBLOCKS * NTHREADS)
#define UNROLL 4

typedef float f32x4 __attribute__((ext_vector_type(4)));
typedef int   i32x4 __attribute__((ext_vector_type(4)));

// Per-element: p = sigmoid(x); a = correct; accumulate t = p - a into bin b.
// Per-bin sum of t IS (sum_conf - sum_acc). One LDS atomic per element,
// fire-and-forget (no dependency chain back into the loop).
__device__ __forceinline__ void accum_elem(float xv, int yv, float* binrow)
{
    float p = 1.0f / (1.0f + __expf(-xv));
    float a = ((xv > 0.0f) == (yv != 0)) ? 1.0f : 0.0f;   // p>0.5 <=> x>0
    float t = (p > 0.0f) ? (p - a) : 0.0f;                // valid mask: p>0
    // digitize(p, linspace(0,1,16), right=True)-1 == ceil(p*15)-1 on (0,1]
    int b = (int)ceilf(p * 15.0f) - 1;
    b = min(max(b, 0), NBINS - 1);
    atomicAdd(&binrow[b], t);                              // ds_add_f32
}

__global__ __launch_bounds__(NTHREADS) void ece_partial_kernel(
    const float* __restrict__ logits,
    const int* __restrict__ labels,
    float* __restrict__ partials,
    int n)
{
    __shared__ float bins[NWAVES][16];   // per-wave rows: no cross-wave races
    const int tid = threadIdx.x;
    const int w   = tid >> 6;
    if (tid < NWAVES * 16) ((float*)bins)[tid] = 0.0f;
    __syncthreads();
    float* binrow = bins[w];

    const int n4 = n >> 2;
    const f32x4* L4 = (const f32x4*)logits;
    const i32x4* Y4 = (const i32x4*)labels;

    const int macroStride = TT * UNROLL;
    const int nMacro = n4 / macroStride;

    int i = blockIdx.x * (NTHREADS * UNROLL) + tid;
    for (int m = 0; m < nMacro; ++m, i += macroStride) {
        f32x4 x[UNROLL];
        i32x4 y[UNROLL];
        #pragma unroll
        for (int u = 0; u < UNROLL; ++u) {
            x[u] = __builtin_nontemporal_load(L4 + i + u * NTHREADS);
            y[u] = __builtin_nontemporal_load(Y4 + i + u * NTHREADS);
        }
        #pragma unroll
        for (int u = 0; u < UNROLL; ++u)
            #pragma unroll
            for (int j = 0; j < 4; ++j)
                accum_elem(x[u][j], y[u][j], binrow);
    }

    // remainder float4s (grid-stride)
    for (int r = nMacro * macroStride + blockIdx.x * NTHREADS + tid;
         r < n4; r += TT) {
        f32x4 x = __builtin_nontemporal_load(L4 + r);
        i32x4 y = __builtin_nontemporal_load(Y4 + r);
        #pragma unroll
        for (int j = 0; j < 4; ++j)
            accum_elem(x[j], y[j], binrow);
    }

    // scalar tail (n not a multiple of 4) — block 0 only
    if (blockIdx.x == 0) {
        for (int r = (n4 << 2) + tid; r < n; r += NTHREADS)
            accum_elem(logits[r], labels[r], binrow);
    }

    __syncthreads();   // drains lgkmcnt: all ds_adds complete

    if (tid < NBINS) {
        float s = 0.0f;
        #pragma unroll
        for (int ww = 0; ww < NWAVES; ++ww) s += bins[ww][tid];
        partials[blockIdx.x * NBINS + tid] = s;
    }
}

// Deterministic fixed-order reduction: D_b = sum_k partials[k][b] (double),
// ece = sum_b |D_b| / n.  960 threads: 64 per bin.
__global__ __launch_bounds__(1024) void ece_final_kernel(
    const float* __restrict__ partials,
    float* __restrict__ out,
    float inv_n)
{
    __shared__ double red[NBINS];
    const int t = threadIdx.x;
    if (t < 64 * NBINS) {
        const int b   = t >> 6;
        const int sub = t & 63;
        double s = 0.0;
        for (int k = sub; k < NBLOCKS; k += 64)
            s += (double)partials[k * NBINS + b];
        #pragma unroll
        for (int m = 32; m >= 1; m >>= 1)
            s += __shfl_xor(s, m, 64);
        if (sub == 0) red[b] = s;
    }
    __syncthreads();
    if (t == 0) {
        double e = 0.0;
        #pragma unroll
        for (int b = 0; b < NBINS; ++b)
            e += fabs(red[b]);
        out[0] = (float)(e * (double)inv_n);
    }
}

extern "C" void kernel_launch(void* const* d_in, const int* in_sizes, int n_in,
                              void* d_out, int out_size, void* d_ws, size_t ws_size,
                              hipStream_t stream)
{
    const float* logits = (const float*)d_in[0];
    const int*   labels = (const int*)d_in[1];
    float* out      = (float*)d_out;
    float* partials = (float*)d_ws;   // NBLOCKS * 15 * 4 B = 120 KiB
    const int n = in_sizes[0];

    ece_partial_kernel<<<NBLOCKS, NTHREADS, 0, stream>>>(logits, labels, partials, n);
    ece_final_kernel<<<1, 1024, 0, stream>>>(partials, out, 1.0f / (float)n);
}

// Round 7
// 97.131 us; speedup vs baseline: 1.9520x; 1.9520x over previous
//
#include <hip/hip_runtime.h>

#define NBINS 15
#define NTHREADS 256
#define NWAVES 4
#define NBLOCKS 2048
#define TT (NBLOCKS * NTHREADS)
#define NXCD 8

typedef float f32x4 __attribute__((ext_vector_type(4)));
typedef int   i32x4 __attribute__((ext_vector_type(4)));

// Streaming pass, register cascade (R2 structure — proven best), with
// XCD-chunked addressing: block bid runs on XCD (bid & 7) [HW round-robin
// dispatch], and reads ONLY from chunk (bid & 7) of the input — each XCD
// streams a private contiguous 33.5 MB slice instead of all 8 XCDs
// interleaving over the full 268 MB.
//
// S[k] = sum over elements with p > k/15 of t = p - acc.
// p > k/15 <=> x > ln(k/(15-k)): compares in logit domain.
// Per-bin (conf - acc) = S[b] - S[b+1]  (S[15] == 0).
__global__ __launch_bounds__(NTHREADS) void ece_partial_kernel(
    const float* __restrict__ logits,
    const int* __restrict__ labels,
    float* __restrict__ partials,
    int n)
{
    const float CE[NBINS] = { -88.72284f,
        -2.63905733f, -1.87180218f, -1.38629436f, -1.01160091f,
        -0.69314718f, -0.40546511f, -0.13353139f,  0.13353139f,
         0.40546511f,  0.69314718f,  1.01160091f,  1.38629436f,
         1.87180218f,  2.63905733f };

    float S[NBINS];
    #pragma unroll
    for (int k = 0; k < NBINS; ++k) S[k] = 0.0f;

    const int tid  = threadIdx.x;
    const int lane = tid & 63;
    const int w    = tid >> 6;
    const int n4   = n >> 2;

    const f32x4* L4 = (const f32x4*)logits;
    const i32x4* Y4 = (const i32x4*)labels;

    if (((n & 3) == 0) && ((n4 & (TT - 1)) == 0)) {
        // ---- fast path: XCD-chunked contiguous streams
        const int xcd  = blockIdx.x & (NXCD - 1);
        const int slot = blockIdx.x >> 3;              // 0..255 within XCD
        const int groupsPerXcd   = n4 >> 3;
        const int groupsPerBlock = n4 / NBLOCKS;
        const int iters          = groupsPerBlock / NTHREADS;
        int idx = xcd * groupsPerXcd + slot * groupsPerBlock + tid;
        for (int m = 0; m < iters; ++m, idx += NTHREADS) {
            f32x4 x = L4[idx];
            i32x4 y = Y4[idx];
            #pragma unroll
            for (int j = 0; j < 4; ++j) {
                float xv = x[j];
                int   yv = y[j];
                float p = 1.0f / (1.0f + __expf(-xv));
                float a = ((xv > 0.0f) == (yv != 0)) ? 1.0f : 0.0f;
                float t = p - a;
                #pragma unroll
                for (int k = 0; k < NBINS; ++k)
                    S[k] += (xv > CE[k]) ? t : 0.0f;
            }
        }
    } else {
        // ---- generic fallback (any n)
        for (int i = blockIdx.x * NTHREADS + tid; i < n4; i += TT) {
            f32x4 x = L4[i];
            i32x4 y = Y4[i];
            #pragma unroll
            for (int j = 0; j < 4; ++j) {
                float xv = x[j];
                int   yv = y[j];
                float p = 1.0f / (1.0f + __expf(-xv));
                float a = ((xv > 0.0f) == (yv != 0)) ? 1.0f : 0.0f;
                float t = p - a;
                #pragma unroll
                for (int k = 0; k < NBINS; ++k)
                    S[k] += (xv > CE[k]) ? t : 0.0f;
            }
        }
        if (blockIdx.x == 0) {          // scalar tail
            for (int r = (n4 << 2) + tid; r < n; r += NTHREADS) {
                float xv = logits[r];
                int   yv = labels[r];
                float p = 1.0f / (1.0f + __expf(-xv));
                float a = ((xv > 0.0f) == (yv != 0)) ? 1.0f : 0.0f;
                float t = p - a;
                #pragma unroll
                for (int k = 0; k < NBINS; ++k)
                    S[k] += (xv > CE[k]) ? t : 0.0f;
            }
        }
    }

    // per-wave butterfly reduce, then cross-wave via tiny LDS
    __shared__ float wavesum[NWAVES][NBINS];
    #pragma unroll
    for (int k = 0; k < NBINS; ++k) {
        float s = S[k];
        #pragma unroll
        for (int m2 = 32; m2 >= 1; m2 >>= 1)
            s += __shfl_xor(s, m2, 64);
        if (lane == 0) wavesum[w][k] = s;
    }
    __syncthreads();

    if (tid < NBINS) {
        float s = 0.0f;
        #pragma unroll
        for (int ww = 0; ww < NWAVES; ++ww) s += wavesum[ww][tid];
        partials[blockIdx.x * NBINS + tid] = s;
    }
}

// Deterministic fixed-order reduction of NBLOCKS x 15 partials, then
// ece = sum_b |S_b - S_{b+1}| / n   (S_15 == 0).
__global__ __launch_bounds__(NTHREADS) void ece_final_kernel(
    const float* __restrict__ partials,
    float* __restrict__ out,
    float inv_n)
{
    __shared__ double red[NBINS];
    const int t = threadIdx.x;
    if (t < 16 * NBINS) {             // 240 threads: 16 per bin
        const int b   = t >> 4;
        const int sub = t & 15;
        double s = 0.0;
        for (int k = sub; k < NBLOCKS; k += 16)
            s += (double)partials[k * NBINS + b];
        s += __shfl_xor(s, 8, 16);
        s += __shfl_xor(s, 4, 16);
        s += __shfl_xor(s, 2, 16);
        s += __shfl_xor(s, 1, 16);
        if (sub == 0) red[b] = s;
    }
    __syncthreads();
    if (t == 0) {
        double e = 0.0;
        #pragma unroll
        for (int b = 0; b < NBINS - 1; ++b)
            e += fabs(red[b] - red[b + 1]);
        e += fabs(red[NBINS - 1]);    // S_15 == 0
        out[0] = (float)(e * (double)inv_n);
    }
}

extern "C" void kernel_launch(void* const* d_in, const int* in_sizes, int n_in,
                              void* d_out, int out_size, void* d_ws, size_t ws_size,
                              hipStream_t stream)
{
    const float* logits = (const float*)d_in[0];
    const int*   labels = (const int*)d_in[1];
    float* out      = (float*)d_out;
    float* partials = (float*)d_ws;   // NBLOCKS * 15 * 4 B = 120 KiB
    const int n = in_sizes[0];

    ece_partial_kernel<<<NBLOCKS, NTHREADS, 0, stream>>>(logits, labels, partials, n);
    ece_final_kernel<<<1, NTHREADS, 0, stream>>>(partials, out, 1.0f / (float)n);
}